// Round 4
// baseline (166.544 us; speedup 1.0000x reference)
//
#include <hip/hip_runtime.h>

// R14: dual-wave-per-SIMD register-crossbar LSTM. B=4096, L=256, H=32, D=2.
// 2048 WGs x 64 threads (single wave). Each wave owns 2 batches, 1 cell per
// lane; 8 waves/CU -> 2 INDEPENDENT waves per SIMD hide each other's
// bpermute/MFMA/trans latency (R12's win) with no barrier or LDS h-exchange
// in the loop (R13's win). R13 post-mortem: 1 wave/SIMD = zero hiding ->
// 1035 cyc/step, ~570 of it the wave's own issue. Issue diet here:
//  - cell u* = 4d+oct (d=m>>1, b=m&1): acc reg r of tile t = gate r of
//    unit 4t+oct -> select only over t=d: 7 cndmask/gate, 28 total.
//  - bias+Wi*spin folded into MFMA C-in: each lane supplies ITS cell's
//    bias in all 8 tiles (correct at t=d, garbage rows never read).
//  - pack h via v_cvt_pk_bf16_f32 + ds_swizzle(xor2) + 1 v_perm (pairs
//    (h[u],h[u+4]) live at even-bit1 lanes; owner(u,b)=16(u&3)+2(u>>2)+b
//    is the IDENTITY on lane ids -> exchange-in = 4 bpermute + 4 v_perm).
//  - head logits: 9th MFMA, Wo in rows 0,1 -> lanes oct==0,m<2 store
//    (S0,S1) to Sbuf.
// Cell math (combined-rcp, 7 transcendentals) carried from R13.

typedef __attribute__((ext_vector_type(8))) short bf16x8;
typedef __attribute__((ext_vector_type(4))) float f32x4;
typedef __attribute__((ext_vector_type(4))) unsigned int u32x4;

#define LOG2E 1.4426950408889634f
#define LN2   0.6931471805599453f

__device__ __forceinline__ float fexp2(float x) { return __builtin_amdgcn_exp2f(x); }
__device__ __forceinline__ float flog2(float x) { return __builtin_amdgcn_logf(x); }
__device__ __forceinline__ float frcp(float x)  { return __builtin_amdgcn_rcpf(x); }

__device__ __forceinline__ float fsig(float x)   { return frcp(1.f + fexp2(-LOG2E * x)); }
__device__ __forceinline__ float ftanh_(float x) { return 1.f - 2.f * frcp(fexp2(2.f * LOG2E * x) + 1.f); }
__device__ __forceinline__ float felu(float x)   { return x > 0.f ? x : fexp2(LOG2E * x) - 1.f; }

__device__ __forceinline__ unsigned short f2bf(float f) {   // RNE f32->bf16
    unsigned u = __builtin_bit_cast(unsigned, f);
    u = (u + 0x7FFFu + ((u >> 16) & 1u)) >> 16;
    return (unsigned short)u;
}

__device__ __forceinline__ unsigned cvtpk_bf16(float a, float b) {
    unsigned r;
    asm("v_cvt_pk_bf16_f32 %0, %1, %2" : "=v"(r) : "v"(a), "v"(b));
    return r;   // lo16 = bf16(a), hi16 = bf16(b), RNE
}

constexpr int Bsz = 4096;

__global__ __launch_bounds__(64, 2) void lstm_r14(
    const int*   __restrict__ x,    // [B, 256]
    const float* __restrict__ Wi,   // [2, 128]
    const float* __restrict__ Wh,   // [32, 128]
    const float* __restrict__ bh,   // [128]
    const float* __restrict__ Wo,   // [32, 2]
    const float* __restrict__ bo,   // [2]
    float*       __restrict__ out)  // [B]
{
    const int lane = threadIdx.x;   // single wave
    const int m    = lane & 15;     // MFMA column
    const int oct  = lane >> 4;
    const int b    = m & 1;         // batch within wave
    const int d    = m >> 1;        // dup group 0..7 -> tile select
    const int b0   = blockIdx.x * 2;

    __shared__ char   spinT[2][260];   // [batch][t] bytes, padded row
    __shared__ float2 Sbuf[256][2];    // raw logits (S0,S1) per (t,batch)

    // ---- stage spins: 64 threads x 8 ints (2 rows x 256) ----
    {
        const int bl = lane >> 5;            // row 0..1
        const int c8 = (lane & 31) * 8;
        const int4* src = reinterpret_cast<const int4*>(x + (b0 + bl) * 256 + c8);
        const int4 v0 = src[0], v1 = src[1];
        const int p0 = (v0.x & 1) | ((v0.y & 1) << 8) | ((v0.z & 1) << 16) | ((v0.w & 1) << 24);
        const int p1 = (v1.x & 1) | ((v1.y & 1) << 8) | ((v1.z & 1) << 16) | ((v1.w & 1) << 24);
        *reinterpret_cast<int*>(&spinT[bl][c8])     = p0;
        *reinterpret_cast<int*>(&spinT[bl][c8 + 4]) = p1;
    }

    // ---- A-frags: tile t, row i=(q=i&3, ur=i>>2) -> gs(q)*Wh[k][32q+4t+ur]
    bf16x8 wfrag[8];
    {
        const int qa = m & 3, ua = m >> 2;
        const float gsq = (qa == 2) ? 2.f * LOG2E : -LOG2E;
#pragma unroll
        for (int t8 = 0; t8 < 8; ++t8) {
            const int colg = 32 * qa + 4 * t8 + ua;
#pragma unroll
            for (int j = 0; j < 8; ++j)
                wfrag[t8][j] = (short)f2bf(gsq * Wh[(8 * oct + j) * 128 + colg]);
        }
    }
    bf16x8 wfragO;   // head: Wo cols in rows 0,1
#pragma unroll
    for (int j = 0; j < 8; ++j)
        wfragO[j] = (m < 2) ? (short)f2bf(Wo[(8 * oct + j) * 2 + m]) : (short)0;

    // ---- this lane's cell + scaled biases ----
    const int u = 4 * d + oct;          // owner(u,b) = 16(u&3)+2(u>>2)+b = lane
    float bv0[4], bvd[4];
#pragma unroll
    for (int r = 0; r < 4; ++r) {
        const float gsr = (r == 2) ? 2.f * LOG2E : -LOG2E;
        const int c0 = 32 * r + u;
        bv0[r] = gsr * (bh[c0] + Wi[c0]);
        bvd[r] = gsr * (Wi[128 + c0] - Wi[c0]);
    }
    const float bo0 = bo[0], bo1 = bo[1];

    // ---- exchange constants ----
    // bpermute addr c: even-pair lane 16c+4oct+b holds (h[8oct+c], h[8oct+c+4])
    const int ad0 = 4 * (16 * 0 + 4 * oct + b);
    const int ad1 = 4 * (16 * 1 + 4 * oct + b);
    const int ad2 = 4 * (16 * 2 + 4 * oct + b);
    const int ad3 = 4 * (16 * 3 + 4 * oct + b);
    // pack selector: bit1(lane)=0 -> p = own.lo | partner.lo<<16, else swapped
    const unsigned selv = (lane & 2) ? 0x01000504u : 0x05040100u;
    const bool db0 = (d & 1), db1 = (d & 2), db2 = (d & 4);

    __syncthreads();   // spins staged

    // ---- peel t=0: input zeros, h=c=0 -> gates = bh ----
    float c = fsig(bh[u]) * ftanh_(bh[64 + u]);
    unsigned p;
    {
        const float h0 = fsig(bh[96 + u]) * ftanh_(c);
        const unsigned r32 = cvtpk_bf16(h0, h0);
        const unsigned sw  = (unsigned)__builtin_amdgcn_ds_swizzle((int)r32, 0x081F); // xor-2
        p = __builtin_amdgcn_perm(sw, r32, selv);
    }

    const f32x4 zero4 = { 0.f, 0.f, 0.f, 0.f };

    auto step = [&](const int t, const float spf) {
        // exchange-in: gather (h[8oct+c], h[8oct+c+4]) pairs
        const int P0 = __builtin_amdgcn_ds_bpermute(ad0, (int)p);
        const int P1 = __builtin_amdgcn_ds_bpermute(ad1, (int)p);
        const int P2 = __builtin_amdgcn_ds_bpermute(ad2, (int)p);
        const int P3 = __builtin_amdgcn_ds_bpermute(ad3, (int)p);

        f32x4 cb;   // this cell's bias -> MFMA C-in (overlaps bpermute wait)
#pragma unroll
        for (int r = 0; r < 4; ++r) cb[r] = fmaf(spf, bvd[r], bv0[r]);

        const unsigned d0 = __builtin_amdgcn_perm((unsigned)P1, (unsigned)P0, 0x05040100u);
        const unsigned d1 = __builtin_amdgcn_perm((unsigned)P3, (unsigned)P2, 0x05040100u);
        const unsigned d2 = __builtin_amdgcn_perm((unsigned)P1, (unsigned)P0, 0x07060302u);
        const unsigned d3 = __builtin_amdgcn_perm((unsigned)P3, (unsigned)P2, 0x07060302u);
        u32x4 hv; hv[0] = d0; hv[1] = d1; hv[2] = d2; hv[3] = d3;
        const bf16x8 hfrag = __builtin_bit_cast(bf16x8, hv);

        f32x4 aq[8];
#pragma unroll
        for (int t8 = 0; t8 < 8; ++t8)
            aq[t8] = __builtin_amdgcn_mfma_f32_16x16x32_bf16(wfrag[t8], hfrag, cb, 0, 0, 0);
        const f32x4 accO = __builtin_amdgcn_mfma_f32_16x16x32_bf16(wfragO, hfrag, zero4, 0, 0, 0);
        if (oct == 0 && m < 2)
            Sbuf[t - 1][m] = make_float2(accO[0], accO[1]);

        // gate select over tile t=d (biased already via C-in)
        float ge[4];
#pragma unroll
        for (int r = 0; r < 4; ++r) {
            const float s0 = db0 ? aq[1][r] : aq[0][r];
            const float s1 = db0 ? aq[3][r] : aq[2][r];
            const float s2 = db0 ? aq[5][r] : aq[4][r];
            const float s3 = db0 ? aq[7][r] : aq[6][r];
            const float s01 = db1 ? s1 : s0;
            const float s23 = db1 ? s3 : s2;
            ge[r] = db2 ? s23 : s01;
        }

        // cell update: e_i=e^{-i}, e_f=e^{-f}, e_g=e^{2g}, e_o=e^{-o}
        const float ei = fexp2(ge[0]), ef = fexp2(ge[1]);
        const float eg = fexp2(ge[2]), eo = fexp2(ge[3]);
        const float P = (1.f + ei) * (1.f + eg);
        const float Q = 1.f + ef;
        const float R = frcp(P * Q);
        c = fmaf(P * R, c, (eg - 1.f) * Q * R);
        const float ec = fexp2(2.f * LOG2E * c);
        const float h  = (ec - 1.f) * frcp((1.f + eo) * (1.f + ec));

        // exchange-out: pack (h[u_even], h[u_odd]) pair dword
        const unsigned r32 = cvtpk_bf16(h, h);
        const unsigned sw  = (unsigned)__builtin_amdgcn_ds_swizzle((int)r32, 0x081F);
        p = __builtin_amdgcn_perm(sw, r32, selv);
    };

    // spins for pair (tb, tb+1) = bytes (tb-1, tb), prefetched a pair ahead
    unsigned sp2 = *reinterpret_cast<const unsigned short*>(&spinT[b][0]);
    for (int tb = 1; tb < 255; tb += 2) {
        const unsigned sp2n =
            *reinterpret_cast<const unsigned short*>(&spinT[b][tb + 1]);
        step(tb,     (float)(sp2 & 0xFFu));
        step(tb + 1, (float)(sp2 >> 8));
        sp2 = sp2n;
    }
    step(255, (float)(sp2 & 0xFFu));   // uses spin 254

    // ---- tail: head logits of step 255 from h_255 ----
    {
        const int P0 = __builtin_amdgcn_ds_bpermute(ad0, (int)p);
        const int P1 = __builtin_amdgcn_ds_bpermute(ad1, (int)p);
        const int P2 = __builtin_amdgcn_ds_bpermute(ad2, (int)p);
        const int P3 = __builtin_amdgcn_ds_bpermute(ad3, (int)p);
        const unsigned d0 = __builtin_amdgcn_perm((unsigned)P1, (unsigned)P0, 0x05040100u);
        const unsigned d1 = __builtin_amdgcn_perm((unsigned)P3, (unsigned)P2, 0x05040100u);
        const unsigned d2 = __builtin_amdgcn_perm((unsigned)P1, (unsigned)P0, 0x07060302u);
        const unsigned d3 = __builtin_amdgcn_perm((unsigned)P3, (unsigned)P2, 0x07060302u);
        u32x4 hv; hv[0] = d0; hv[1] = d1; hv[2] = d2; hv[3] = d3;
        const bf16x8 hfrag = __builtin_bit_cast(bf16x8, hv);
        const f32x4 accO = __builtin_amdgcn_mfma_f32_16x16x32_bf16(wfragO, hfrag, zero4, 0, 0, 0);
        if (oct == 0 && m < 2)
            Sbuf[255][m] = make_float2(accO[0], accO[1]);
    }
    __syncthreads();

    // ---- post phase: ELU + log-softmax + sum over t ----
    float lp = 0.f;
    {
        const int bpost = lane & 1;     // batch
        const int tc    = lane >> 1;    // time chunk 0..31
#pragma unroll
        for (int i = 0; i < 8; ++i) {
            const int t = tc * 8 + i;
            const float2 sv = Sbuf[t][bpost];
            const int sp = spinT[bpost][t];
            const float o0 = felu(sv.x + bo0);
            const float o1 = felu(sv.y + bo1);
            const float mx = fmaxf(o0, o1), mn = fminf(o0, o1);
            const float lse = mx + LN2 * flog2(1.f + fexp2(LOG2E * (mn - mx)));
            lp += (sp ? o1 : o0) - lse;
        }
    }
    lp += __shfl_xor(lp, 2, 64);    // reduce over tc bits (keep b separate)
    lp += __shfl_xor(lp, 4, 64);
    lp += __shfl_xor(lp, 8, 64);
    lp += __shfl_xor(lp, 16, 64);
    lp += __shfl_xor(lp, 32, 64);
    if (lane < 2) out[b0 + lane] = 0.5f * lp;
}

extern "C" void kernel_launch(void* const* d_in, const int* in_sizes, int n_in,
                              void* d_out, int out_size, void* d_ws, size_t ws_size,
                              hipStream_t stream) {
    const int*   x  = (const int*)d_in[0];
    const float* Wi = (const float*)d_in[1];
    const float* Wh = (const float*)d_in[2];
    const float* bh = (const float*)d_in[3];
    const float* Wo = (const float*)d_in[4];
    const float* bo = (const float*)d_in[5];
    float* out = (float*)d_out;

    // 2048 single-wave WGs -> 8 waves/CU -> 2 independent waves per SIMD.
    lstm_r14<<<dim3(Bsz / 2), dim3(64), 0, stream>>>(x, Wi, Wh, bh, Wo, bo, out);
}

// Round 5
// 157.173 us; speedup vs baseline: 1.0596x; 1.0596x over previous
//
#include <hip/hip_runtime.h>

// R15: 2-wave workgroup, 4 batches/WG, 4 WGs/CU. B=4096, L=256, H=32, D=2.
// 1024 WGs x 128 threads. Design point between R12 (4-wave WG: lean issue,
// coarse 2-chain/CU granularity -> 240cyc barrier stall, 84.5us) and R14
// (wave-autonomous: 8 chains/CU but issue-bound at 663 VALU-cyc/SIMD/step,
// 123us). Here per SIMD: 2 waves from 2 DIFFERENT WGs; 4 independent
// step-chains per CU; barrier spans only 2 waves.
//  - tile q = gate q; row i = unit 16w+i; wave w owns units 16w..16w+15.
//    Lane (m,oct): batch b=m&3, rho=m>>2, cell u=16w+4oct+rho -> its 4
//    gates are acc[q][rho]: 3 cndmask x 4 = 12 select ops, no exchange.
//  - h through LDS dbuf hbuf[2][4][32] (512B): ds_write_b16 + 2-wave
//    barrier + ds_read_b128 (broadcast, conflict-free).
//  - head logits: 5th MFMA (Wo in rows 0,1) alternating wave by (t-1)&1
//    -> 0.5 MFMA/wave/step; S(t-1) = acc[0..1] at oct==0, col m<4.
//  - bias+Wi*spin: 4 fmaf off-chain + 4 adds post-select (C-in=0).
//  - 24KB static LDS pad -> exactly 4 WGs/CU; grid 1024 = 4 x 256 CUs.
// Cell math (combined-rcp, 7 transcendentals), 2-step unroll with spin
// pair prefetch, post-loop ELU/log-softmax carried from R12/R14.

typedef __attribute__((ext_vector_type(8))) short bf16x8;
typedef __attribute__((ext_vector_type(4))) float f32x4;

#define LOG2E 1.4426950408889634f
#define LN2   0.6931471805599453f

__device__ __forceinline__ float fexp2(float x) { return __builtin_amdgcn_exp2f(x); }
__device__ __forceinline__ float flog2(float x) { return __builtin_amdgcn_logf(x); }
__device__ __forceinline__ float frcp(float x)  { return __builtin_amdgcn_rcpf(x); }

__device__ __forceinline__ float fsig(float x)   { return frcp(1.f + fexp2(-LOG2E * x)); }
__device__ __forceinline__ float ftanh_(float x) { return 1.f - 2.f * frcp(fexp2(2.f * LOG2E * x) + 1.f); }
__device__ __forceinline__ float felu(float x)   { return x > 0.f ? x : fexp2(LOG2E * x) - 1.f; }

__device__ __forceinline__ unsigned short f2bf(float f) {   // RNE f32->bf16
    unsigned u = __builtin_bit_cast(unsigned, f);
    u = (u + 0x7FFFu + ((u >> 16) & 1u)) >> 16;
    return (unsigned short)u;
}

constexpr int Bsz = 4096;

__global__ __launch_bounds__(128, 2) void lstm_r15(
    const int*   __restrict__ x,    // [B, 256]
    const float* __restrict__ Wi,   // [2, 128]
    const float* __restrict__ Wh,   // [32, 128]
    const float* __restrict__ bh,   // [128]
    const float* __restrict__ Wo,   // [32, 2]
    const float* __restrict__ bo,   // [2]
    float*       __restrict__ out)  // [B]
{
    const int tid  = threadIdx.x;
    const int w    = tid >> 6;      // wave 0..1: owns units 16w..16w+15
    const int lane = tid & 63;
    const int m    = lane & 15;     // MFMA column
    const int oct  = lane >> 4;
    const int b    = m & 3;         // batch within WG
    const int rho  = m >> 2;        // dup index -> acc reg select
    const int b0   = blockIdx.x * 4;

    __shared__ char   spinT[4][260];                 // [batch][t] bytes
    __shared__ float2 Sbuf[256][4];                  // raw logits per (t,batch)
    __shared__ __align__(16) short hbuf[2][4][32];   // h dbuf [buf][batch][unit]
    __shared__ float  red[2][4];
    __shared__ char   occ_pad[24576];                // cap residency at 4 WGs/CU
    if ((int)blockIdx.x == -1) occ_pad[0] = (char)tid;   // keep pad live

    // ---- stage spins: 128 threads x 8 bytes (4 rows x 256) ----
    {
        const int bl = tid >> 5;            // row 0..3
        const int c8 = (tid & 31) * 8;
        const int4* src = reinterpret_cast<const int4*>(x + (b0 + bl) * 256 + c8);
        const int4 v0 = src[0], v1 = src[1];
        const int p0 = (v0.x & 1) | ((v0.y & 1) << 8) | ((v0.z & 1) << 16) | ((v0.w & 1) << 24);
        const int p1 = (v1.x & 1) | ((v1.y & 1) << 8) | ((v1.z & 1) << 16) | ((v1.w & 1) << 24);
        *reinterpret_cast<int*>(&spinT[bl][c8])     = p0;
        *reinterpret_cast<int*>(&spinT[bl][c8 + 4]) = p1;
    }

    // ---- A-frags: tile q = gate q, row m = unit 16w+m, k = 8oct+j ----
    bf16x8 wfrag[4];
#pragma unroll
    for (int q = 0; q < 4; ++q) {
        const float gs = (q == 2) ? 2.f * LOG2E : -LOG2E;
        const int colg = 32 * q + 16 * w + m;
#pragma unroll
        for (int j = 0; j < 8; ++j)
            wfrag[q][j] = (short)f2bf(gs * Wh[(8 * oct + j) * 128 + colg]);
    }
    bf16x8 wfragO;   // head: Wo cols in rows 0,1
#pragma unroll
    for (int j = 0; j < 8; ++j)
        wfragO[j] = (m < 2) ? (short)f2bf(Wo[(8 * oct + j) * 2 + m]) : (short)0;

    // ---- this lane's cell + scaled biases ----
    const int u = 16 * w + 4 * oct + rho;
    float bv0[4], bvd[4];
#pragma unroll
    for (int q = 0; q < 4; ++q) {
        const float gs = (q == 2) ? 2.f * LOG2E : -LOG2E;
        const int c0 = 32 * q + u;
        bv0[q] = gs * (bh[c0] + Wi[c0]);
        bvd[q] = gs * (Wi[128 + c0] - Wi[c0]);
    }
    const float bo0 = bo[0], bo1 = bo[1];

    // ---- peel t=0: input zeros, h=c=0 -> gates = bh ----
    float c = fsig(bh[u]) * ftanh_(bh[64 + u]);
    hbuf[0][b][u] = (short)f2bf(fsig(bh[96 + u]) * ftanh_(c));
    __syncthreads();   // spins + h0 visible

    const f32x4 zero4 = { 0.f, 0.f, 0.f, 0.f };
    const bool rb0 = (rho & 1) != 0, rb1 = (rho & 2) != 0;

    // one step; rbuf/wbuf/hw compile-time at each call site
    auto step = [&](const int t, const int rbuf, const int wbuf,
                    const float spf, const int hw) {
        const bf16x8 hfrag =
            *reinterpret_cast<const bf16x8*>(&hbuf[rbuf][b][8 * oct]);

        // bias (off the MFMA chain)
        const float cb0 = fmaf(spf, bvd[0], bv0[0]);
        const float cb1 = fmaf(spf, bvd[1], bv0[1]);
        const float cb2 = fmaf(spf, bvd[2], bv0[2]);
        const float cb3 = fmaf(spf, bvd[3], bv0[3]);

        f32x4 acc[4];
#pragma unroll
        for (int q = 0; q < 4; ++q)
            acc[q] = __builtin_amdgcn_mfma_f32_16x16x32_bf16(wfrag[q], hfrag, zero4, 0, 0, 0);

        // head logits of step t-1, alternating wave
        if (w == hw) {
            const f32x4 aO = __builtin_amdgcn_mfma_f32_16x16x32_bf16(wfragO, hfrag, zero4, 0, 0, 0);
            if (oct == 0 && m < 4)
                Sbuf[t - 1][m] = make_float2(aO[0], aO[1]);
        }

        // gate select: reg rho of tile q (3 cndmask each)
        float ge[4];
#pragma unroll
        for (int q = 0; q < 4; ++q) {
            const float s01 = rb0 ? acc[q][1] : acc[q][0];
            const float s23 = rb0 ? acc[q][3] : acc[q][2];
            ge[q] = rb1 ? s23 : s01;
        }

        // cell update: e_i=e^{-i}, e_f=e^{-f}, e_g=e^{2g}, e_o=e^{-o}
        const float a0 = cb0 + ge[0];
        const float a1 = cb1 + ge[1];
        const float a2 = cb2 + ge[2];
        const float a3 = cb3 + ge[3];
        const float ei = fexp2(a0), ef = fexp2(a1);
        const float eg = fexp2(a2), eo = fexp2(a3);
        const float P = (1.f + ei) * (1.f + eg);
        const float Q = 1.f + ef;
        const float R = frcp(P * Q);
        c = fmaf(P * R, c, (eg - 1.f) * Q * R);
        const float ec = fexp2(2.f * LOG2E * c);
        const float h  = (ec - 1.f) * frcp((1.f + eo) * (1.f + ec));
        hbuf[wbuf][b][u] = (short)f2bf(h);
        __syncthreads();   // h_t visible to both waves
    };

    // spins for pair (tb, tb+1) = bytes (tb-1, tb), prefetched a pair ahead
    unsigned sp2 = *reinterpret_cast<const unsigned short*>(&spinT[b][0]);
    for (int tb = 1; tb < 255; tb += 2) {
        const unsigned sp2n =
            *reinterpret_cast<const unsigned short*>(&spinT[b][tb + 1]);
        step(tb,     0, 1, (float)(sp2 & 0xFFu), 0);   // (tb-1)&1 == 0
        step(tb + 1, 1, 0, (float)(sp2 >> 8),    1);   // (tb)&1   == 1
        sp2 = sp2n;
    }
    step(255, 0, 1, (float)(sp2 & 0xFFu), 0);   // uses spin 254; S(254) by wave 0

    // ---- tail: head logits of step 255 (h_255 in hbuf[1]) by wave 1 ----
    if (w == 1) {
        const bf16x8 hfrag = *reinterpret_cast<const bf16x8*>(&hbuf[1][b][8 * oct]);
        const f32x4 aO = __builtin_amdgcn_mfma_f32_16x16x32_bf16(wfragO, hfrag, zero4, 0, 0, 0);
        if (oct == 0 && m < 4)
            Sbuf[255][m] = make_float2(aO[0], aO[1]);
    }
    __syncthreads();

    // ---- post phase: ELU + log-softmax + sum over t, 32 time-chunks ----
    float lp = 0.f;
    {
        const int bpost = tid & 3;      // batch
        const int tc    = tid >> 2;     // time chunk 0..31
#pragma unroll
        for (int i = 0; i < 8; ++i) {
            const int t = tc * 8 + i;
            const float2 sv = Sbuf[t][bpost];
            const int sp = spinT[bpost][t];
            const float o0 = felu(sv.x + bo0);
            const float o1 = felu(sv.y + bo1);
            const float mx = fmaxf(o0, o1), mn = fminf(o0, o1);
            const float lse = mx + LN2 * flog2(1.f + fexp2(LOG2E * (mn - mx)));
            lp += (sp ? o1 : o0) - lse;
        }
    }
    lp += __shfl_xor(lp, 4, 64);    // reduce over tc bits within wave
    lp += __shfl_xor(lp, 8, 64);
    lp += __shfl_xor(lp, 16, 64);
    lp += __shfl_xor(lp, 32, 64);
    if (lane < 4) red[w][lane] = lp;
    __syncthreads();
    if (tid < 4) out[b0 + tid] = 0.5f * (red[0][tid] + red[1][tid]);
}

extern "C" void kernel_launch(void* const* d_in, const int* in_sizes, int n_in,
                              void* d_out, int out_size, void* d_ws, size_t ws_size,
                              hipStream_t stream) {
    const int*   x  = (const int*)d_in[0];
    const float* Wi = (const float*)d_in[1];
    const float* Wh = (const float*)d_in[2];
    const float* bh = (const float*)d_in[3];
    const float* Wo = (const float*)d_in[4];
    const float* bo = (const float*)d_in[5];
    float* out = (float*)d_out;

    // 1024 two-wave WGs; ~34KB LDS/WG caps residency at exactly 4 WGs/CU
    // -> 8 waves/CU = 2 independent waves per SIMD, 4 step-chains per CU.
    lstm_r15<<<dim3(Bsz / 4), dim3(128), 0, stream>>>(x, Wi, Wh, bh, Wo, bo, out);
}